// Round 15
// baseline (135.298 us; speedup 1.0000x reference)
//
#include <hip/hip_runtime.h>
#include <math.h>

// Problem constants (from reference)
#define NDIM   8
#define NBINS  64
#define LOG_BETA   (-13.815510557964274f)  // log(1e-6)
#define LN2F       0.69314718055994531f
// mesh is geometric: boundary_j (original coords) = x1L*(1.2^j-1)/0.2, j=0..32
// bin index from |x|: g = log2(1 + ALPHA*|x|) / log2(1.2);  ALPHA = (1.2^32-1)/10
#define ALPHA      34.0821892f
#define INV_LOG2R  3.80178401692393f       // 1/log2(1.2)
#define L2R        0.26303440583379378f    // log2(1.2)

typedef float f32x4 __attribute__((ext_vector_type(4)));

// Two threads per point: lane g handles float4 half (g&1) of point (g>>1).
// Skeleton = round-14 winner (40.2us: 512-thr blocks, 1 dim/wave prep, plain
// stores). Changes vs R14: (1) prefetch 3->4 deep (every depth step so far
// gained 1-2us); (2) prep reduce eliminated — the inclusive scan's lane-63
// value IS the normalization sum (Sum a_k == s algebraically), so scan
// unscaled cell integrals, broadcast lane 63, scale afterwards; the fixed
// beta-boundary contribution folds in analytically (b_pre).
__global__ __launch_bounds__(512, 4) void cdfq_fused(const float* __restrict__ x,
                                                     const float* __restrict__ logdet_in,
                                                     const float* __restrict__ p,
                                                     float* __restrict__ y_out,
                                                     float* __restrict__ ld_out,
                                                     int n)
{
    __shared__ float4 stbl[NDIM * NBINS];  // [d][k]: {v1, slope, F_pre, mesh_k}

    const int t  = threadIdx.x;
    const int T  = gridDim.x * blockDim.x;         // work-item stride
    const int i0 = blockIdx.x * blockDim.x + t;
    const int G  = 2 * n;                          // work items = half-points
    const int iters = G / T;                       // 8 on the bench shape
    const f32x4* xv4 = (const f32x4*)x;

    // ---- prologue: 4-deep prefetch issued BEFORE prep so the first four
    //      memory latencies hide behind prep's VALU/shuffle work ----
    f32x4 X0, X1, X2, X3; float L0, L1, Lc2, Lc3;
    if (iters > 0) { X0 = xv4[i0];         L0  = logdet_in[i0 >> 1]; }
    if (iters > 1) { X1 = xv4[i0 + T];     L1  = logdet_in[(i0 + T) >> 1]; }
    if (iters > 2) { X2 = xv4[i0 + 2 * T]; Lc2 = logdet_in[(i0 + 2 * T) >> 1]; }
    if (iters > 3) { X3 = xv4[i0 + 3 * T]; Lc3 = logdet_in[(i0 + 3 * T) >> 1]; }
    __builtin_amdgcn_sched_barrier(0);   // do not sink these below prep

    // ---- prep: 8 waves, each builds ONE dim of the table fully in-register.
    //      Serial chain: exp -> a -> scan(6) -> bcast -> scale -> write.
    //      (Old 6-shuffle reduce removed: scan lane 63 == normalization sum.)
    {
        const int lane = t & 63;
        const int d    = t >> 6;                   // wave index == dim, 0..7
        const float pw32 = exp2f(32.0f * L2R);     // 1.2^32
        const float inv  = 0.5f / (pw32 - 1.0f);
        auto meshf = [&](float tt) {               // normalized mesh coordinate
            float fidx = tt - 32.0f;
            float pw = exp2f(fabsf(fidx) * L2R);
            float r  = (pw - 1.0f) * inv;
            return 0.5f + ((fidx >= 0.0f) ? r : -r);
        };
        const float m0  = meshf((float)lane);          // mesh[lane]
        const float m1  = meshf((float)(lane + 1));    // mesh[lane+1]
        const float el  = m1 - m0;                     // elmt[lane]
        const float e0e63 = 2.0f * (meshf(1.0f) - meshf(0.0f)); // elmt[0]+elmt[63]

        float ep = 0.0f;
        if (lane < 63) ep = __expf(p[lane * NDIM + d]);  // interior node lane+1
        float epu = __shfl_up(ep, 1);
        if (lane == 0) epu = 0.0f;                       // no interior node at 0

        // unscaled cell integral (variable part): a_k = el_k*(ep_{k-1}+ep_k)/2
        const float a = 0.5f * el * (epu + ep);
        // inclusive scan of a
        float v = a;
#pragma unroll
        for (int off = 1; off < 64; off <<= 1) {
            float u = __shfl_up(v, off);
            if (lane >= off) v += u;
        }
        // lane 63 of the scan == Sum a_k == normalization sum s (identity:
        // Sum_k el_k*(ep_{k-1}+ep_k)/2 == Sum_j ep_j*(el_j+el_{j+1})/2)
        const float s = __shfl(v, 63);
        const float scale = (1.0f - e0e63 * 5e-7f) / s;
        // fixed beta-boundary part of the exclusive prefix: only cell_0 holds
        // a constant 0.5*BETA*el_0 term (el_0 = e0e63/2) -> 2.5e-7*e0e63
        const float b_pre = (lane > 0) ? (2.5e-7f * e0e63) : 0.0f;

        const float Fpre = fmaf(scale, v - a, b_pre);   // exclusive prefix, scaled
        const float pdl = (lane == 0)  ? 1e-6f : scale * epu;  // pdf[lane]
        const float pdn = (lane == 63) ? 1e-6f : scale * ep;   // pdf[lane+1]
        stbl[(d << 6) | lane] = make_float4(pdl, (pdn - pdl) / el, Fpre, m0);
    }
    __syncthreads();

    // ---- iteration-invariant hoists: half-point parity never changes ----
    const float4* tbl = &stbl[((i0 & 1) << 2) << 6];   // dims 0-3 or 4-7 base
    const bool evenlane = ((i0 & 1) == 0);

    // ---- per-half-point body: 4 dims, one shfl_xor to combine logdet ----
    auto body = [&](f32x4 Xv, float Lin, int g) {
        float yd[4];
        float contrib;

        float mx = fmaxf(fmaxf(fabsf(Xv[0]), fabsf(Xv[1])),
                         fmaxf(fabsf(Xv[2]), fabsf(Xv[3])));

        if (!__any(mx >= 10.0f)) {
            // ---- fast path (always taken for N(0,1) input): no boundary
            //      handling, no cov selects, no LOG_BETA bookkeeping ----
            float dd4[4];
#pragma unroll
            for (int dl = 0; dl < 4; ++dl) {
                float xo = Xv[dl];
                float xs = fmaf(xo, 0.05f, 0.5f);        // (x+10)/20 to 1 ulp
                // analytic bin: one v_log_f32
                float gg = __log2f(fmaf(ALPHA, fabsf(xo), 1.0f)) * INV_LOG2R;
                int jf = (int)fminf(gg, 31.0f);
                int k  = ((xo >= 0.0f) ? 32 : 31) ^ jf;  // 32+jf / 31-jf

                f32x4 tv = *(const f32x4*)&tbl[(dl << 6) + k];
                float xm = xs - tv[3];
                yd[dl]  = fmaf(fmaf(xm, fmaf(0.5f * xm, tv[1], tv[0]), tv[2]),
                               20.0f, -10.0f);
                dd4[dl] = fmaf(xm, tv[1], tv[0]);
            }
            contrib = (__log2f(dd4[0] * dd4[1]) + __log2f(dd4[2] * dd4[3])) * LN2F;
        } else {
            // ---- full reference path (rare) ----
            float dd4[4];
            float extra = 0.0f;
#pragma unroll
            for (int dl = 0; dl < 4; ++dl) {
                float xo = Xv[dl];
                float xs = fmaf(xo, 0.05f, 0.5f);
                float gg = __log2f(fmaf(ALPHA, fabsf(xo), 1.0f)) * INV_LOG2R;
                int jf = (int)fminf(gg, 31.0f);
                int k  = ((xo >= 0.0f) ? 32 : 31) ^ jf;

                f32x4 tv = *(const f32x4*)&tbl[(dl << 6) + k];
                float xm = xs - tv[3];
                bool cov = (fabsf(xo) < 10.0f);          // == (0 <= xs < 1)

                float yc = fmaf(xm, fmaf(0.5f * xm, tv[1], tv[0]), tv[2]);
                float dv = fmaf(xm, tv[1], tv[0]);
                float yy = cov ? yc : xs;
                dd4[dl]  = cov ? dv : 1.0f;

                yy = fmaf(yy, 20.0f, -10.0f);
                if (yy > 10.0f)  { yy = fmaf(1e-6f, yy - 10.0f, 10.0f);  extra += LOG_BETA; }
                if (yy < -10.0f) { yy = fmaf(1e-6f, yy + 10.0f, -10.0f); extra += LOG_BETA; }
                yd[dl] = yy;
            }
            contrib = fmaf(__log2f(dd4[0] * dd4[1]) + __log2f(dd4[2] * dd4[3]),
                           LN2F, extra);
        }

        float cross = __shfl_xor(contrib, 1);      // partner half-point

        f32x4 yv = { yd[0], yd[1], yd[2], yd[3] };
        *((f32x4*)y_out + g) = yv;                 // PLAIN store (acks at L2)
        if (evenlane)
            ld_out[g >> 1] = Lin + contrib + cross;
    };

    // ---- main loop: guard-free 5-stage (4 loads in flight) software pipeline ----
    for (int j = 0; j < iters; ++j) {
        f32x4 Xn; float Ln;
        const bool more = (j + 4 < iters);         // wave-uniform
        if (more) {
            int gx = i0 + (j + 4) * T;
            Xn = xv4[gx];
            Ln = logdet_in[gx >> 1];
        }
        __builtin_amdgcn_sched_barrier(0);         // keep prefetch above the compute

        body(X0, L0, i0 + j * T);

        X0 = X1; L0 = L1;
        X1 = X2; L1 = Lc2;
        X2 = X3; Lc2 = Lc3;
        if (more) { X3 = Xn; Lc3 = Ln; }
    }

    // ---- remainder (never runs when T | G; kept for generality) ----
    for (int g = i0 + iters * T; g < G; g += T) {
        body(xv4[g], logdet_in[g >> 1], g);        // pairs never split: G is even,
                                                   // partner is adjacent lane
    }
}

extern "C" void kernel_launch(void* const* d_in, const int* in_sizes, int n_in,
                              void* d_out, int out_size, void* d_ws, size_t ws_size,
                              hipStream_t stream) {
    const float* x      = (const float*)d_in[0];   // [N, 8]
    const float* logdet = (const float*)d_in[1];   // [N, 1]
    const float* p      = (const float*)d_in[2];   // [63, 8]

    const int n = in_sizes[1];                     // N points
    float* y_out  = (float*)d_out;                 // [N*8]
    float* ld_out = (float*)d_out + (size_t)n * NDIM;  // [N]

    const int block = 512;
    int grid = 1024;                               // T=524288 (iters=8), 4 blk/CU
                                                   // x 8 waves = 32 waves/CU
    if ((long long)grid * block > 2LL * n) grid = (2 * n + block - 1) / block;
    cdfq_fused<<<grid, block, 0, stream>>>(x, logdet, p, y_out, ld_out, n);
}

// Round 16
// 132.137 us; speedup vs baseline: 1.0239x; 1.0239x over previous
//
#include <hip/hip_runtime.h>
#include <math.h>

// Problem constants (from reference)
#define NDIM   8
#define NBINS  64
#define LOG_BETA   (-13.815510557964274f)  // log(1e-6)
#define LN2F       0.69314718055994531f
// mesh is geometric: boundary_j (original coords) = x1L*(1.2^j-1)/0.2, j=0..32
// bin index from |x|: g = log2(1 + ALPHA*|x|) / log2(1.2);  ALPHA = (1.2^32-1)/10
#define ALPHA      34.0821892f
#define INV_LOG2R  3.80178401692393f       // 1/log2(1.2)
#define L2R        0.26303440583379378f    // log2(1.2)

typedef float f32x4 __attribute__((ext_vector_type(4)));

// Two threads per point: lane g handles float4 half (g&1) of point (g>>1).
// Skeleton = round-14 winner (40.2us: 512-thr blocks, 1 dim/wave prep, plain
// stores, 3-deep prefetch). SINGLE CHANGE vs R14 (unbundling R15's pair):
// prep reduce eliminated via the scan identity — the inclusive scan's lane-63
// value IS the normalization sum (Sum a_k == s), so scan unscaled cell
// integrals, broadcast lane 63, scale afterwards; the fixed beta-boundary
// contribution folds in analytically (b_pre). R15's 4-deep prefetch (the
// other bundled change, suspected regressor: 2x rotation copies + idle slots
// on the last 4 of 8 iterations) is NOT included.
__global__ __launch_bounds__(512, 4) void cdfq_fused(const float* __restrict__ x,
                                                     const float* __restrict__ logdet_in,
                                                     const float* __restrict__ p,
                                                     float* __restrict__ y_out,
                                                     float* __restrict__ ld_out,
                                                     int n)
{
    __shared__ float4 stbl[NDIM * NBINS];  // [d][k]: {v1, slope, F_pre, mesh_k}

    const int t  = threadIdx.x;
    const int T  = gridDim.x * blockDim.x;         // work-item stride
    const int i0 = blockIdx.x * blockDim.x + t;
    const int G  = 2 * n;                          // work items = half-points
    const int iters = G / T;                       // 8 on the bench shape
    const f32x4* xv4 = (const f32x4*)x;

    // ---- prologue: 3-deep prefetch issued BEFORE prep so the first three
    //      memory latencies hide behind prep's VALU/shuffle work ----
    f32x4 X0, X1, X2; float L0, L1, Lc2;
    if (iters > 0) { X0 = xv4[i0];         L0  = logdet_in[i0 >> 1]; }
    if (iters > 1) { X1 = xv4[i0 + T];     L1  = logdet_in[(i0 + T) >> 1]; }
    if (iters > 2) { X2 = xv4[i0 + 2 * T]; Lc2 = logdet_in[(i0 + 2 * T) >> 1]; }
    __builtin_amdgcn_sched_barrier(0);   // do not sink these below prep

    // ---- prep: 8 waves, each builds ONE dim of the table fully in-register.
    //      Serial chain: exp -> a -> scan(6) -> bcast -> scale -> write.
    //      (Old 6-shuffle reduce removed: scan lane 63 == normalization sum.)
    {
        const int lane = t & 63;
        const int d    = t >> 6;                   // wave index == dim, 0..7
        const float pw32 = exp2f(32.0f * L2R);     // 1.2^32
        const float inv  = 0.5f / (pw32 - 1.0f);
        auto meshf = [&](float tt) {               // normalized mesh coordinate
            float fidx = tt - 32.0f;
            float pw = exp2f(fabsf(fidx) * L2R);
            float r  = (pw - 1.0f) * inv;
            return 0.5f + ((fidx >= 0.0f) ? r : -r);
        };
        const float m0  = meshf((float)lane);          // mesh[lane]
        const float m1  = meshf((float)(lane + 1));    // mesh[lane+1]
        const float el  = m1 - m0;                     // elmt[lane]
        const float e0e63 = 2.0f * (meshf(1.0f) - meshf(0.0f)); // elmt[0]+elmt[63]

        float ep = 0.0f;
        if (lane < 63) ep = __expf(p[lane * NDIM + d]);  // interior node lane+1
        float epu = __shfl_up(ep, 1);
        if (lane == 0) epu = 0.0f;                       // no interior node at 0

        // unscaled cell integral (variable part): a_k = el_k*(ep_{k-1}+ep_k)/2
        const float a = 0.5f * el * (epu + ep);
        // inclusive scan of a
        float v = a;
#pragma unroll
        for (int off = 1; off < 64; off <<= 1) {
            float u = __shfl_up(v, off);
            if (lane >= off) v += u;
        }
        // lane 63 of the scan == Sum a_k == normalization sum s (identity:
        // Sum_k el_k*(ep_{k-1}+ep_k)/2 == Sum_j ep_j*(el_j+el_{j+1})/2)
        const float s = __shfl(v, 63);
        const float scale = (1.0f - e0e63 * 5e-7f) / s;
        // fixed beta-boundary part of the exclusive prefix: only cell_0 holds
        // a constant 0.5*BETA*el_0 term (el_0 = e0e63/2) -> 2.5e-7*e0e63
        const float b_pre = (lane > 0) ? (2.5e-7f * e0e63) : 0.0f;

        const float Fpre = fmaf(scale, v - a, b_pre);   // exclusive prefix, scaled
        const float pdl = (lane == 0)  ? 1e-6f : scale * epu;  // pdf[lane]
        const float pdn = (lane == 63) ? 1e-6f : scale * ep;   // pdf[lane+1]
        stbl[(d << 6) | lane] = make_float4(pdl, (pdn - pdl) / el, Fpre, m0);
    }
    __syncthreads();

    // ---- iteration-invariant hoists: half-point parity never changes ----
    const float4* tbl = &stbl[((i0 & 1) << 2) << 6];   // dims 0-3 or 4-7 base
    const bool evenlane = ((i0 & 1) == 0);

    // ---- per-half-point body: 4 dims, one shfl_xor to combine logdet ----
    auto body = [&](f32x4 Xv, float Lin, int g) {
        float yd[4];
        float contrib;

        float mx = fmaxf(fmaxf(fabsf(Xv[0]), fabsf(Xv[1])),
                         fmaxf(fabsf(Xv[2]), fabsf(Xv[3])));

        if (!__any(mx >= 10.0f)) {
            // ---- fast path (always taken for N(0,1) input): no boundary
            //      handling, no cov selects, no LOG_BETA bookkeeping ----
            float dd4[4];
#pragma unroll
            for (int dl = 0; dl < 4; ++dl) {
                float xo = Xv[dl];
                float xs = fmaf(xo, 0.05f, 0.5f);        // (x+10)/20 to 1 ulp
                // analytic bin: one v_log_f32
                float gg = __log2f(fmaf(ALPHA, fabsf(xo), 1.0f)) * INV_LOG2R;
                int jf = (int)fminf(gg, 31.0f);
                int k  = ((xo >= 0.0f) ? 32 : 31) ^ jf;  // 32+jf / 31-jf

                f32x4 tv = *(const f32x4*)&tbl[(dl << 6) + k];
                float xm = xs - tv[3];
                yd[dl]  = fmaf(fmaf(xm, fmaf(0.5f * xm, tv[1], tv[0]), tv[2]),
                               20.0f, -10.0f);
                dd4[dl] = fmaf(xm, tv[1], tv[0]);
            }
            contrib = (__log2f(dd4[0] * dd4[1]) + __log2f(dd4[2] * dd4[3])) * LN2F;
        } else {
            // ---- full reference path (rare) ----
            float dd4[4];
            float extra = 0.0f;
#pragma unroll
            for (int dl = 0; dl < 4; ++dl) {
                float xo = Xv[dl];
                float xs = fmaf(xo, 0.05f, 0.5f);
                float gg = __log2f(fmaf(ALPHA, fabsf(xo), 1.0f)) * INV_LOG2R;
                int jf = (int)fminf(gg, 31.0f);
                int k  = ((xo >= 0.0f) ? 32 : 31) ^ jf;

                f32x4 tv = *(const f32x4*)&tbl[(dl << 6) + k];
                float xm = xs - tv[3];
                bool cov = (fabsf(xo) < 10.0f);          // == (0 <= xs < 1)

                float yc = fmaf(xm, fmaf(0.5f * xm, tv[1], tv[0]), tv[2]);
                float dv = fmaf(xm, tv[1], tv[0]);
                float yy = cov ? yc : xs;
                dd4[dl]  = cov ? dv : 1.0f;

                yy = fmaf(yy, 20.0f, -10.0f);
                if (yy > 10.0f)  { yy = fmaf(1e-6f, yy - 10.0f, 10.0f);  extra += LOG_BETA; }
                if (yy < -10.0f) { yy = fmaf(1e-6f, yy + 10.0f, -10.0f); extra += LOG_BETA; }
                yd[dl] = yy;
            }
            contrib = fmaf(__log2f(dd4[0] * dd4[1]) + __log2f(dd4[2] * dd4[3]),
                           LN2F, extra);
        }

        float cross = __shfl_xor(contrib, 1);      // partner half-point

        f32x4 yv = { yd[0], yd[1], yd[2], yd[3] };
        *((f32x4*)y_out + g) = yv;                 // PLAIN store (acks at L2)
        if (evenlane)
            ld_out[g >> 1] = Lin + contrib + cross;
    };

    // ---- main loop: guard-free 4-stage (3 loads in flight) software pipeline ----
    for (int j = 0; j < iters; ++j) {
        f32x4 Xn; float Ln;
        const bool more = (j + 3 < iters);         // wave-uniform
        if (more) {
            int gx = i0 + (j + 3) * T;
            Xn = xv4[gx];
            Ln = logdet_in[gx >> 1];
        }
        __builtin_amdgcn_sched_barrier(0);         // keep prefetch above the compute

        body(X0, L0, i0 + j * T);

        X0 = X1; L0 = L1;
        X1 = X2; L1 = Lc2;
        if (more) { X2 = Xn; Lc2 = Ln; }
    }

    // ---- remainder (never runs when T | G; kept for generality) ----
    for (int g = i0 + iters * T; g < G; g += T) {
        body(xv4[g], logdet_in[g >> 1], g);        // pairs never split: G is even,
                                                   // partner is adjacent lane
    }
}

extern "C" void kernel_launch(void* const* d_in, const int* in_sizes, int n_in,
                              void* d_out, int out_size, void* d_ws, size_t ws_size,
                              hipStream_t stream) {
    const float* x      = (const float*)d_in[0];   // [N, 8]
    const float* logdet = (const float*)d_in[1];   // [N, 1]
    const float* p      = (const float*)d_in[2];   // [63, 8]

    const int n = in_sizes[1];                     // N points
    float* y_out  = (float*)d_out;                 // [N*8]
    float* ld_out = (float*)d_out + (size_t)n * NDIM;  // [N]

    const int block = 512;
    int grid = 1024;                               // T=524288 (iters=8), 4 blk/CU
                                                   // x 8 waves = 32 waves/CU
    if ((long long)grid * block > 2LL * n) grid = (2 * n + block - 1) / block;
    cdfq_fused<<<grid, block, 0, stream>>>(x, logdet, p, y_out, ld_out, n);
}